// Round 3
// baseline (11.001 us; speedup 1.0000x reference)
//
#include <hip/hip_runtime.h>

// AssociativeEmbeddingLoss on MI355X — single dispatch, fence-free fusion.
// pred:   (64, 1, 512, 512) f32
// target: (64, 1, 512, 512) f32
// match:  (64, 128, 2, 2)   int32
// out:    2 floats: (pull_all, push_all)
//
// pull_b = sum_i (tl_i - me_i)^2 + (br_i - me_i)^2, me = (tl+br)/2
// push_b = sum_{i != j} max(0, 1 - |me_i - me_j|)
// out0 = 0.25 * sum_b pull_b / 128
// out1 = 0.25 * sum_b push_b / (128*127)
//
// Cross-block handoff: the per-image partial IS the flag. Producer packs
// (pull+1.0f, push) into one u64 and publishes with a RELAXED agent-scope
// atomic store (single-copy atomic at the coherence point — no threadfence,
// no buffer_wbl2). Consumer (block 0, wave 0) polls with relaxed agent
// atomic loads (no buffer_inv). Validity: (int32)(hi_word) >= 0x3F800000
//  - valid:  pull+1.0f >= 1.0  -> bits in [0x3F800000, ~0x43000000)  PASS
//  - fresh ws zeros:  0x00000000 < 0x3F800000                        FAIL
//  - harness poison:  0xAAAAAAAA negative as int32                   FAIL
//  - post-consume reset 0                                            FAIL
// Consumer resets flags to 0 after reading => clean state every replay
// (kernel completion implicitly flushes; stream serializes replays).

#define AE_B      64
#define AE_NGT    128
#define AE_W      512
#define AE_HW     (512 * 512)

__device__ __forceinline__ unsigned long long ae_pack(float pull, float push) {
    union { float f; unsigned u; } a, b;
    a.f = pull + 1.0f;   // tag: valid iff hi >= 1.0f (sign bit clear)
    b.f = push;
    return ((unsigned long long)a.u << 32) | (unsigned long long)b.u;
}

__global__ __launch_bounds__(AE_NGT) void ae_loss_fused(
    const float* __restrict__ pred,
    const float* __restrict__ target,
    const int*   __restrict__ match,
    float*       __restrict__ out,                    // [2]
    unsigned long long* __restrict__ flags)           // [B] packed partials
{
    const int b = blockIdx.x;   // image
    const int t = threadIdx.x;  // 0..127 = gt index

    __shared__ float s_me[AE_NGT];
    __shared__ float s_red[4];  // {pull_w0, push_w0, pull_w1, push_w1}

    // match[b][t] = {ty, tx, by, bx} — one int4 per thread, coalesced.
    const int4 m = reinterpret_cast<const int4*>(match)[b * AE_NGT + t];
    const float tl = pred  [b * AE_HW + m.x * AE_W + m.y];
    const float br = target[b * AE_HW + m.z * AE_W + m.w];
    const float me = 0.5f * (tl + br);

    const float dtl = tl - me;
    const float dbr = br - me;
    float pull = dtl * dtl + dbr * dbr;

    s_me[t] = me;
    __syncthreads();

    float push = 0.0f;
#pragma unroll
    for (int j = 0; j < AE_NGT; ++j) {
        // LDS broadcast read (all lanes same address) — conflict-free.
        const float v = 1.0f - fabsf(me - s_me[j]);
        if (j != t) push += fmaxf(v, 0.0f);
    }

    // Wave-64 down-reduce, then combine the block's two waves via LDS.
#pragma unroll
    for (int off = 32; off > 0; off >>= 1) {
        pull += __shfl_down(pull, off, 64);
        push += __shfl_down(push, off, 64);
    }
    if ((t & 63) == 0) {
        s_red[(t >> 6) * 2 + 0] = pull;
        s_red[(t >> 6) * 2 + 1] = push;
    }
    __syncthreads();

    if (b != 0) {
        if (t == 0) {
            __hip_atomic_store(&flags[b],
                               ae_pack(s_red[0] + s_red[2], s_red[1] + s_red[3]),
                               __ATOMIC_RELAXED, __HIP_MEMORY_SCOPE_AGENT);
        }
        return;
    }

    // ---- block 0 finisher: wave 0 only (no __syncthreads below!) ----
    if (t >= 64) return;

    float p, q;
    if (t == 0) {
        p = s_red[0] + s_red[2];
        q = s_red[1] + s_red[3];
    } else {
        // lane t waits for image t's packed partial (t = 1..63)
        unsigned long long v;
        for (;;) {
            v = __hip_atomic_load(&flags[t], __ATOMIC_RELAXED,
                                  __HIP_MEMORY_SCOPE_AGENT);
            if ((int)(unsigned)(v >> 32) >= 0x3F800000) break;
            __builtin_amdgcn_s_sleep(1);
        }
        union { unsigned u; float f; } hi, lo;
        hi.u = (unsigned)(v >> 32);
        lo.u = (unsigned)v;
        p = hi.f - 1.0f;
        q = lo.f;
        // reset for the next replay
        __hip_atomic_store(&flags[t], 0ull,
                           __ATOMIC_RELAXED, __HIP_MEMORY_SCOPE_AGENT);
    }

#pragma unroll
    for (int off = 32; off > 0; off >>= 1) {
        p += __shfl_down(p, off, 64);
        q += __shfl_down(q, off, 64);
    }
    if (t == 0) {
        out[0] = p * (0.25f / 128.0f);
        out[1] = q * (0.25f / (128.0f * 127.0f));
    }
}

extern "C" void kernel_launch(void* const* d_in, const int* in_sizes, int n_in,
                              void* d_out, int out_size, void* d_ws, size_t ws_size,
                              hipStream_t stream) {
    const float* pred   = (const float*)d_in[0];
    const float* target = (const float*)d_in[1];
    const int*   match  = (const int*)d_in[2];
    float* out = (float*)d_out;
    unsigned long long* flags = (unsigned long long*)d_ws;  // 64 * 8 = 512 B

    ae_loss_fused<<<AE_B, AE_NGT, 0, stream>>>(pred, target, match, out, flags);
}